// Round 3
// baseline (2061.058 us; speedup 1.0000x reference)
//
#include <hip/hip_runtime.h>
#include <cmath>
#include <cstdint>
#include <cstddef>
#include <climits>

#define N_SRC 65536
#define N_TGT 1024
#define DIM   256
#define TAU_INV (1.0f/0.07f)
#define LOSS_EPS 1e-6f
#define TOPSEL 512
#define NBI (N_SRC/128)     // 512 row-blocks
#define RSLICE 16
#define RS_ELEMS (N_SRC/RSLICE)   // 4096

typedef __bf16 bf16x8 __attribute__((ext_vector_type(8)));
typedef float  f32x4  __attribute__((ext_vector_type(4)));

// ---------------- bf16 split helpers ------------------------------------------------
__device__ __forceinline__ unsigned short f2bf(float x) {
  unsigned u = __float_as_uint(x);
  unsigned r = (u + 0x7fffu + ((u >> 16) & 1u)) >> 16;
  return (unsigned short)r;
}
__device__ __forceinline__ float bf2f(unsigned short h) {
  return __uint_as_float(((unsigned)h) << 16);
}

// ---------------- top-5 insertion helpers -------------------------------------------
__device__ __forceinline__ void insert5_vi(float v[5], int id[5], float nv, int ni) {
  bool beats_last = (nv > v[4]) || (nv == v[4] && ni < id[4]);
  if (!beats_last) return;
  #pragma unroll
  for (int p = 4; p > 0; --p) {
    bool up = (nv > v[p-1]) || (nv == v[p-1] && ni < id[p-1]);
    if (up) { v[p] = v[p-1]; id[p] = id[p-1]; }
    else    { v[p] = nv; id[p] = ni; return; }
  }
  v[0] = nv; id[0] = ni;
}
__device__ __forceinline__ void insert5_v(float v[5], float nv) {
  if (!(nv > v[4])) return;
  #pragma unroll
  for (int p = 4; p > 0; --p) {
    if (nv > v[p-1]) v[p] = v[p-1];
    else { v[p] = nv; return; }
  }
  v[0] = nv;
}
__device__ __forceinline__ void wave_merge5_vi(float v[5], int id[5]) {
  #pragma unroll
  for (int off = 1; off < 64; off <<= 1) {
    float pv[5]; int pi[5];
    #pragma unroll
    for (int u = 0; u < 5; ++u) {
      pv[u] = __shfl_xor(v[u], off, 64);
      pi[u] = __shfl_xor(id[u], off, 64);
    }
    #pragma unroll
    for (int u = 0; u < 5; ++u) insert5_vi(v, id, pv[u], pi[u]);
  }
}
__device__ __forceinline__ void wave_merge5_v(float v[5]) {
  #pragma unroll
  for (int off = 1; off < 64; off <<= 1) {
    float pv[5];
    #pragma unroll
    for (int u = 0; u < 5; ++u) pv[u] = __shfl_xor(v[u], off, 64);
    #pragma unroll
    for (int u = 0; u < 5; ++u) insert5_v(v, pv[u]);
  }
}

// ---------------- K1: row-normalize + split fp32 -> (hi, lo) bf16 -------------------
__global__ __launch_bounds__(256) void k_norm_split(const float* __restrict__ X,
                                                    unsigned short* __restrict__ hi,
                                                    unsigned short* __restrict__ lo) {
  int wave = threadIdx.x >> 6, lane = threadIdx.x & 63;
  int row  = blockIdx.x * 4 + wave;
  float4 v = reinterpret_cast<const float4*>(X + (size_t)row * DIM)[lane];
  float ss = v.x*v.x + v.y*v.y + v.z*v.z + v.w*v.w;
  #pragma unroll
  for (int o = 32; o > 0; o >>= 1) ss += __shfl_xor(ss, o, 64);
  float r = 1.0f / sqrtf(ss);
  v.x *= r; v.y *= r; v.z *= r; v.w *= r;
  ushort4 h, l;
  h.x = f2bf(v.x); l.x = f2bf(v.x - bf2f(h.x));
  h.y = f2bf(v.y); l.y = f2bf(v.y - bf2f(h.y));
  h.z = f2bf(v.z); l.z = f2bf(v.z - bf2f(h.z));
  h.w = f2bf(v.w); l.w = f2bf(v.w - bf2f(h.w));
  reinterpret_cast<ushort4*>(hi + (size_t)row * DIM)[lane] = h;
  reinterpret_cast<ushort4*>(lo + (size_t)row * DIM)[lane] = l;
}

// ---------------- K2: K-expanded bf16 MFMA GEMM (m97 structure) ---------------------
// Logical K'=768 over 3 segments: (Ahi,Bhi) + (Alo,Bhi) + (Ahi,Blo) = hh + lh + hl.
// 128x128 tile, BK=32, 4 waves 2x2, 4x4 frags of 16x16x32, 16 INDEPENDENT MFMA/step.
// Double-buffered: stage tile t+1 before computing t; one barrier per step.
// Epilogue: fp32 sim store + per-(block,col) top-5(val,idx) + per-(block,col) sum-exp.
__device__ __forceinline__ void gl_lds(const unsigned short* g, unsigned short* d) {
  __builtin_amdgcn_global_load_lds(
      (const __attribute__((address_space(1))) unsigned int*)g,
      (__attribute__((address_space(3))) unsigned int*)d, 16, 0, 0);
}

__global__ __launch_bounds__(256, 3) void k_gemm_topk(
    const unsigned short* __restrict__ Ahi, const unsigned short* __restrict__ Alo,
    const unsigned short* __restrict__ Bhi, const unsigned short* __restrict__ Blo,
    float* __restrict__ simT,                // chunk-local [cols][N_SRC]
    float* __restrict__ p1v, int* __restrict__ p1i, float* __restrict__ pse,
    int j_off, int nbjc)
{
  __shared__ unsigned short bufA[2 * 128 * 32];   // [As | Bs] even tiles; epi scratch
  __shared__ unsigned short bufB[2 * 128 * 32];   // odd tiles

  const int tid  = threadIdx.x;
  const int lane = tid & 63;
  const int w    = tid >> 6;
  const int wm   = w & 1;
  const int wn   = w >> 1;

  // bijective XCD-locality remap: consecutive blocks on one XCD share the A panel
  const int d  = blockIdx.x;          // grid.x = NBI * nbjc
  const int c  = d & 7;
  const int kk = d >> 3;
  const int bj = kk % nbjc;
  const int bi = (kk / nbjc) * 8 + c;
  const int i0  = bi * 128;
  const int j0l = bj * 128;
  const int j0g = j_off + j0l;

  f32x4 acc[4][4];
  #pragma unroll
  for (int a = 0; a < 4; ++a)
    #pragma unroll
    for (int b = 0; b < 4; ++b) acc[a][b] = f32x4{0.f, 0.f, 0.f, 0.f};

  const int srow = (w << 5) + (lane >> 2);
  const int scol = (lane & 3) << 3;
  const unsigned short* gAh = Ahi + (size_t)(i0  + srow) * DIM + scol;
  const unsigned short* gAl = Alo + (size_t)(i0  + srow) * DIM + scol;
  const unsigned short* gBh = Bhi + (size_t)(j0g + srow) * DIM + scol;
  const unsigned short* gBl = Blo + (size_t)(j0g + srow) * DIM + scol;

  auto stage = [&](const unsigned short* gA, const unsigned short* gB, int kc,
                   unsigned short* s) {
    gl_lds(gA + kc,          s + (w << 5) * 32);
    gl_lds(gA + kc + 16*DIM, s + ((w << 5) + 16) * 32);
    gl_lds(gB + kc,          s + 128*32 + (w << 5) * 32);
    gl_lds(gB + kc + 16*DIM, s + 128*32 + ((w << 5) + 16) * 32);
  };

  const int fr = lane & 15;
  const int fk = (lane >> 4) << 3;

  stage(gAh, gBh, 0, bufA);
  __syncthreads();

  #pragma unroll
  for (int t = 0; t < 24; ++t) {
    const unsigned short* cur = (t & 1) ? bufB : bufA;
    unsigned short*       nxt = (t & 1) ? bufA : bufB;
    if (t < 23) {
      const int tn = t + 1, sg = tn >> 3, kc = (tn & 7) << 5;
      stage(sg == 1 ? gAl : gAh, sg == 2 ? gBl : gBh, kc, nxt);
    }
    const unsigned short* As = cur;
    const unsigned short* Bs = cur + 128*32;
    bf16x8 a[4], b[4];
    #pragma unroll
    for (int rf = 0; rf < 4; ++rf)
      a[rf] = *(const bf16x8*)&As[((wm << 6) + (rf << 4) + fr) * 32 + fk];
    #pragma unroll
    for (int cf = 0; cf < 4; ++cf)
      b[cf] = *(const bf16x8*)&Bs[((wn << 6) + (cf << 4) + fr) * 32 + fk];
    #pragma unroll
    for (int rf = 0; rf < 4; ++rf)
      #pragma unroll
      for (int cf = 0; cf < 4; ++cf)
        acc[rf][cf] = __builtin_amdgcn_mfma_f32_16x16x32_bf16(a[rf], b[cf], acc[rf][cf], 0, 0, 0);
    __syncthreads();
  }

  // ---- epilogue. acc map: col n = wn*64+cf*16+(lane&15); row m = wm*64+rf*16+(lane>>4)*4+reg
  // (1) fp32 sim store (full-line coalesced via L2 merge)
  #pragma unroll
  for (int rf = 0; rf < 4; ++rf) {
    const int m_base = (wm << 6) + (rf << 4) + ((lane >> 4) << 2);
    #pragma unroll
    for (int cf = 0; cf < 4; ++cf) {
      const int n = (wn << 6) + (cf << 4) + (lane & 15);
      *reinterpret_cast<float4*>(&simT[(size_t)(j0l + n) * N_SRC + i0 + m_base]) =
          make_float4(acc[rf][cf][0], acc[rf][cf][1], acc[rf][cf][2], acc[rf][cf][3]);
    }
  }
  // (2) per-column top-5 (val, global idx) + sum-exp over this block's 128 rows
  float* ep_v  = reinterpret_cast<float*>(bufA);          // [2][128][5]
  int*   ep_i  = reinterpret_cast<int*>(bufA) + 1280;     // [2][128][5]
  float* ep_se = reinterpret_cast<float*>(bufA) + 2560;   // [2][128]
  #pragma unroll
  for (int cf = 0; cf < 4; ++cf) {
    float tv[5]; int ti[5]; float sse = 0.f;
    #pragma unroll
    for (int u = 0; u < 5; ++u) { tv[u] = -INFINITY; ti[u] = INT_MAX; }
    #pragma unroll
    for (int rf = 0; rf < 4; ++rf) {
      const int mb = i0 + (wm << 6) + (rf << 4) + ((lane >> 4) << 2);
      #pragma unroll
      for (int r = 0; r < 4; ++r) {
        insert5_vi(tv, ti, acc[rf][cf][r], mb + r);
        sse += __expf(acc[rf][cf][r] * TAU_INV);
      }
    }
    #pragma unroll
    for (int off = 16; off < 64; off <<= 1) {
      sse += __shfl_xor(sse, off, 64);
      float pv[5]; int pi[5];
      #pragma unroll
      for (int u = 0; u < 5; ++u) { pv[u] = __shfl_xor(tv[u], off, 64); pi[u] = __shfl_xor(ti[u], off, 64); }
      #pragma unroll
      for (int u = 0; u < 5; ++u) insert5_vi(tv, ti, pv[u], pi[u]);
    }
    if (lane < 16) {
      const int col = (wn << 6) + (cf << 4) + lane;
      #pragma unroll
      for (int u = 0; u < 5; ++u) { ep_v[(wm*128 + col)*5 + u] = tv[u]; ep_i[(wm*128 + col)*5 + u] = ti[u]; }
      ep_se[wm*128 + col] = sse;
    }
  }
  __syncthreads();
  if (tid < 128) {
    float v[5]; int id[5];
    #pragma unroll
    for (int u = 0; u < 5; ++u) { v[u] = -INFINITY; id[u] = INT_MAX; }
    #pragma unroll
    for (int h = 0; h < 2; ++h)
      #pragma unroll
      for (int u = 0; u < 5; ++u)
        insert5_vi(v, id, ep_v[(h*128 + tid)*5 + u], ep_i[(h*128 + tid)*5 + u]);
    const size_t o = ((size_t)(j0g + tid) * NBI + bi) * 5;
    #pragma unroll
    for (int u = 0; u < 5; ++u) { p1v[o+u] = v[u]; p1i[o+u] = id[u]; }
    pse[(size_t)(j0g + tid) * NBI + bi] = ep_se[tid] + ep_se[128 + tid];
  }
}

// ---------------- K3: merge row-block top-5s -> assigned label per column -----------
__global__ __launch_bounds__(256) void k_assign2(const float* __restrict__ p1v,
                                                 const int* __restrict__ p1i,
                                                 const int* __restrict__ labels,
                                                 int* __restrict__ assigned, int j_off) {
  const int w = threadIdx.x >> 6, lane = threadIdx.x & 63;
  const int j = j_off + blockIdx.x * 4 + w;
  const float* pv = p1v + (size_t)j * NBI * 5;
  const int*   pi = p1i + (size_t)j * NBI * 5;
  float v[5]; int id[5];
  #pragma unroll
  for (int u = 0; u < 5; ++u) { v[u] = -INFINITY; id[u] = INT_MAX; }
  for (int b = lane; b < NBI; b += 64) {
    #pragma unroll
    for (int u = 0; u < 5; ++u) insert5_vi(v, id, pv[b*5 + u], pi[b*5 + u]);
  }
  wave_merge5_vi(v, id);
  if (lane == 0) {
    int lab[5];
    #pragma unroll
    for (int a = 0; a < 5; ++a) lab[a] = labels[id[a]];
    int bestSc = INT_MIN, bestA = 0;
    #pragma unroll
    for (int a = 0; a < 5; ++a) {
      int cnt = 0;
      #pragma unroll
      for (int b = 0; b < 5; ++b) cnt += (lab[b] == lab[a]) ? 1 : 0;
      int sc = cnt * 1000000 - lab[a];
      if (sc > bestSc) { bestSc = sc; bestA = a; }
    }
    assigned[j] = lab[bestA];
  }
}

// ---------------- K4: reader over stored sim: sem + matched/unmatched top-5 ---------
__global__ __launch_bounds__(256) void k_part2r(const float* __restrict__ simT,
                                                const int* __restrict__ labels,
                                                const int* __restrict__ assigned,
                                                float* __restrict__ p2r, int j_off) {
  const int s    = blockIdx.x;     // slice 0..15
  const int jloc = blockIdx.y;
  const int tid  = threadIdx.x;
  const int lane = tid & 63, w = tid >> 6;
  const int asg  = assigned[j_off + jloc];
  const float4* row = reinterpret_cast<const float4*>(simT + (size_t)jloc * N_SRC)
                      + s * (RS_ELEMS/4) + tid;
  const int4* lab4 = reinterpret_cast<const int4*>(labels) + s * (RS_ELEMS/4) + tid;

  float sem = 0.f;
  float mt[5], ut[5];
  #pragma unroll
  for (int u = 0; u < 5; ++u) { mt[u] = -INFINITY; ut[u] = -INFINITY; }
  #pragma unroll
  for (int t = 0; t < 4; ++t) {
    float4 v = row[t * 256];
    int4   l = lab4[t * 256];
    if (l.x == asg) { sem += __expf(v.x * TAU_INV); insert5_v(mt, v.x); } else insert5_v(ut, v.x);
    if (l.y == asg) { sem += __expf(v.y * TAU_INV); insert5_v(mt, v.y); } else insert5_v(ut, v.y);
    if (l.z == asg) { sem += __expf(v.z * TAU_INV); insert5_v(mt, v.z); } else insert5_v(ut, v.z);
    if (l.w == asg) { sem += __expf(v.w * TAU_INV); insert5_v(mt, v.w); } else insert5_v(ut, v.w);
  }
  #pragma unroll
  for (int o = 32; o > 0; o >>= 1) sem += __shfl_xor(sem, o, 64);
  wave_merge5_v(mt);
  wave_merge5_v(ut);
  __shared__ float wmt[4*5], wut[4*5], wsm[4];
  if (lane == 0) {
    #pragma unroll
    for (int u = 0; u < 5; ++u) { wmt[w*5+u] = mt[u]; wut[w*5+u] = ut[u]; }
    wsm[w] = sem;
  }
  __syncthreads();
  if (tid == 0) {
    float m3[5], u3[5];
    #pragma unroll
    for (int u = 0; u < 5; ++u) { m3[u] = -INFINITY; u3[u] = -INFINITY; }
    for (int cc = 0; cc < 20; ++cc) { insert5_v(m3, wmt[cc]); insert5_v(u3, wut[cc]); }
    const size_t o = ((size_t)(j_off + jloc) * RSLICE + s) * 11;
    p2r[o] = wsm[0] + wsm[1] + wsm[2] + wsm[3];
    #pragma unroll
    for (int u = 0; u < 5; ++u) { p2r[o+1+u] = m3[u]; p2r[o+6+u] = u3[u]; }
  }
}

// ---------------- K5: merge partials -> scores, contrast ----------------------------
__global__ __launch_bounds__(256) void k_score2(const float* __restrict__ p2r,
                                                const float* __restrict__ pse,
                                                float* __restrict__ scores,
                                                float* __restrict__ contrast, int j_off) {
  const int w = threadIdx.x >> 6, lane = threadIdx.x & 63;
  const int j = j_off + blockIdx.x * 4 + w;
  const float* ps = pse + (size_t)j * NBI;
  float se = 0.f;
  #pragma unroll
  for (int b = 0; b < NBI/64; ++b) se += ps[b*64 + lane];
  float sem = 0.f;
  float mt[5], ut[5];
  #pragma unroll
  for (int u = 0; u < 5; ++u) { mt[u] = -INFINITY; ut[u] = -INFINITY; }
  if (lane < RSLICE) {
    const float* p = p2r + ((size_t)j * RSLICE + lane) * 11;
    sem = p[0];
    #pragma unroll
    for (int u = 0; u < 5; ++u) { insert5_v(mt, p[1+u]); insert5_v(ut, p[6+u]); }
  }
  #pragma unroll
  for (int o = 32; o > 0; o >>= 1) { se += __shfl_xor(se, o, 64); sem += __shfl_xor(sem, o, 64); }
  wave_merge5_v(mt);
  wave_merge5_v(ut);
  if (lane == 0) {
    float nln = 0.f, nun = 0.f;
    #pragma unroll
    for (int u = 0; u < 5; ++u) {
      if (mt[u] > -1e30f) nln += mt[u];
      if (ut[u] > -1e30f) nun += ut[u];
    }
    scores[j]   = nln / nun;
    contrast[j] = sem / se;
  }
}

// ---------------- K6: top-512 selection + loss --------------------------------------
__global__ __launch_bounds__(1024) void k_finalize(const float* __restrict__ scores,
                                                   const float* __restrict__ contrast,
                                                   float* __restrict__ out) {
  __shared__ float sc[N_TGT];
  __shared__ float red[N_TGT];
  const int j = threadIdx.x;
  sc[j] = scores[j];
  __syncthreads();
  float my = sc[j];
  int rank = 0;
  for (int m = 0; m < N_TGT; ++m) {
    float s = sc[m];
    rank += ((s > my) || (s == my && m < j)) ? 1 : 0;
  }
  red[j] = (rank < TOPSEL) ? logf(contrast[j] + LOSS_EPS) : 0.0f;
  __syncthreads();
  for (int s = 512; s > 0; s >>= 1) { if (j < s) red[j] += red[j+s]; __syncthreads(); }
  if (j == 0) out[0] = -red[0] / (float)TOPSEL;
}

// ---------------- launcher ----------------------------------------------------------
extern "C" void kernel_launch(void* const* d_in, const int* in_sizes, int n_in,
                              void* d_out, int out_size, void* d_ws, size_t ws_size,
                              hipStream_t stream) {
  const float* S      = (const float*)d_in[0];
  const int*   labels = (const int*)d_in[1];
  const float* T      = (const float*)d_in[2];
  float* out = (float*)d_out;

  float* ws = (float*)d_ws;
  float* scores    = ws;                                        // 1024
  float* contrastA = scores + N_TGT;                            // 1024
  int*   assigned  = (int*)(contrastA + N_TGT);                 // 1024
  float* p1v       = (float*)(assigned + N_TGT);                // 1024*512*5
  int*   p1i       = (int*)(p1v + (size_t)N_TGT*NBI*5);         // 1024*512*5
  float* pse       = (float*)(p1i + (size_t)N_TGT*NBI*5);       // 1024*512
  float* p2r       = pse + (size_t)N_TGT*NBI;                   // 1024*16*11
  unsigned short* Shi = (unsigned short*)(p2r + (size_t)N_TGT*RSLICE*11);
  unsigned short* Slo = Shi + (size_t)N_SRC*DIM;
  unsigned short* Thi = Slo + (size_t)N_SRC*DIM;
  unsigned short* Tlo = Thi + (size_t)N_TGT*DIM;
  float* simbuf       = (float*)(Tlo + (size_t)N_TGT*DIM);

  size_t head  = (size_t)(simbuf - ws);
  size_t avail = (ws_size / 4 > head) ? (ws_size / 4 - head) : 0;
  int cols = 128;
  if      (avail >= (size_t)1024 * N_SRC) cols = 1024;
  else if (avail >= (size_t)512  * N_SRC) cols = 512;
  else if (avail >= (size_t)256  * N_SRC) cols = 256;

  k_norm_split<<<N_TGT/4, 256, 0, stream>>>(T, Thi, Tlo);
  k_norm_split<<<N_SRC/4, 256, 0, stream>>>(S, Shi, Slo);

  for (int j_off = 0; j_off < N_TGT; j_off += cols) {
    const int nbjc = cols / 128;
    k_gemm_topk<<<NBI * nbjc, 256, 0, stream>>>(Shi, Slo, Thi, Tlo, simbuf,
                                                p1v, p1i, pse, j_off, nbjc);
    k_assign2<<<cols/4, 256, 0, stream>>>(p1v, p1i, labels, assigned, j_off);
    k_part2r<<<dim3(RSLICE, cols), 256, 0, stream>>>(simbuf, labels, assigned, p2r, j_off);
    k_score2<<<cols/4, 256, 0, stream>>>(p2r, pse, scores, contrastA, j_off);
  }
  k_finalize<<<1, 1024, 0, stream>>>(scores, contrastA, out);
}